// Round 1
// baseline (201.220 us; speedup 1.0000x reference)
//
#include <hip/hip_runtime.h>
#include <hip/hip_bf16.h>

typedef __bf16 bf16;
typedef __bf16 bf16x8 __attribute__((ext_vector_type(8)));
typedef __bf16 bf16x4 __attribute__((ext_vector_type(4)));
typedef float f32x4 __attribute__((ext_vector_type(4)));

#define GLOAD_LDS16(g, l) \
  __builtin_amdgcn_global_load_lds((const __attribute__((address_space(1))) void*)(g), \
                                   (__attribute__((address_space(3))) void*)(l), 16, 0, 0)

// ---------------- cast f32 -> bf16 (vectorized) ----------------
__global__ void cast_bf16_kernel(const float* __restrict__ in, bf16* __restrict__ out, int n4) {
  int i = blockIdx.x * blockDim.x + threadIdx.x;
  if (i >= n4) return;
  float4 v = ((const float4*)in)[i];
  bf16x4 o;
  o.x = (bf16)v.x; o.y = (bf16)v.y; o.z = (bf16)v.z; o.w = (bf16)v.w;
  ((bf16x4*)out)[i] = o;
}

// ---------------- transpose + cast weights: W[K][N] f32 -> Wt[N][K] bf16 ----------------
__global__ void transpose_cast_w(const float* __restrict__ W, bf16* __restrict__ Wt, int K, int N) {
  __shared__ float tile[32][33];
  const int n0 = blockIdx.x * 32, k0 = blockIdx.y * 32;
  const int tx = threadIdx.x, ty = threadIdx.y;
#pragma unroll
  for (int i = 0; i < 32; i += 8)
    tile[ty + i][tx] = W[(size_t)(k0 + ty + i) * N + n0 + tx];
  __syncthreads();
#pragma unroll
  for (int i = 0; i < 32; i += 8)
    Wt[(size_t)(n0 + ty + i) * K + k0 + tx] = (bf16)tile[tx][ty + i];
}

// ---------------- V transpose: V[bh][s][d] -> Vt[bh][d][s] (bf16) ----------------
__global__ void vtrans_kernel(const bf16* __restrict__ V, bf16* __restrict__ Vt) {
  __shared__ bf16 tile[32][34];
  const int bh = blockIdx.z;
  const int s0 = blockIdx.x * 32, d0 = blockIdx.y * 32;
  const int tx = threadIdx.x, ty = threadIdx.y;
#pragma unroll
  for (int i = 0; i < 32; i += 8)
    tile[ty + i][tx] = V[((size_t)bh * 2048 + s0 + ty + i) * 64 + d0 + tx];
  __syncthreads();
#pragma unroll
  for (int i = 0; i < 32; i += 8)
    Vt[((size_t)bh * 64 + d0 + ty + i) * 2048 + s0 + tx] = tile[tx][ty + i];
}

// ---------------- GEMM: C[M][N] = A[M][K] * Bt[N][K]^T + bias ----------------
// EPI 0: fp32 out, natural layout. EPI 1: bf16 out in [bh][t][d] (Q). EPI 2: split KV -> K,V [bh][s][d].
template <int EPI>
__global__ __launch_bounds__(256) void gemm_bf16_kernel(
    const bf16* __restrict__ A, const bf16* __restrict__ Bt,
    const float* __restrict__ bias,
    void* __restrict__ out0, void* __restrict__ out1,
    int M, int N, int K) {
  __shared__ __align__(16) bf16 As[128 * 32];
  __shared__ __align__(16) bf16 Bs[128 * 32];

  const int tid = threadIdx.x;
  const int lane = tid & 63;
  const int w = tid >> 6;
  const int wr = w >> 1, wc = w & 1;
  const int g = lane >> 4, r16 = lane & 15;
  const int m0 = blockIdx.y * 128, n0 = blockIdx.x * 128;

  const int c0 = tid, c1 = tid + 256;
  const bf16* Ag0 = A + (size_t)(m0 + (c0 >> 2)) * K + (c0 & 3) * 8;
  const bf16* Ag1 = A + (size_t)(m0 + (c1 >> 2)) * K + (c1 & 3) * 8;
  const bf16* Bg0 = Bt + (size_t)(n0 + (c0 >> 2)) * K + (c0 & 3) * 8;
  const bf16* Bg1 = Bt + (size_t)(n0 + (c1 >> 2)) * K + (c1 & 3) * 8;
  bf16* As0 = As + w * 512;
  bf16* As1 = As + 2048 + w * 512;
  bf16* Bs0 = Bs + w * 512;
  bf16* Bs1 = Bs + 2048 + w * 512;

  f32x4 acc[4][4] = {};

  for (int k0 = 0; k0 < K; k0 += 32) {
    __syncthreads();
    GLOAD_LDS16(Ag0 + k0, As0);
    GLOAD_LDS16(Ag1 + k0, As1);
    GLOAD_LDS16(Bg0 + k0, Bs0);
    GLOAD_LDS16(Bg1 + k0, Bs1);
    __syncthreads();
    bf16x8 af[4], bfr[4];
#pragma unroll
    for (int i = 0; i < 4; i++)
      af[i] = *(const bf16x8*)(As + (wr * 64 + i * 16 + r16) * 32 + g * 8);
#pragma unroll
    for (int i = 0; i < 4; i++)
      bfr[i] = *(const bf16x8*)(Bs + (wc * 64 + i * 16 + r16) * 32 + g * 8);
#pragma unroll
    for (int mi = 0; mi < 4; mi++)
#pragma unroll
      for (int ni = 0; ni < 4; ni++)
        acc[mi][ni] = __builtin_amdgcn_mfma_f32_16x16x32_bf16(af[mi], bfr[ni], acc[mi][ni], 0, 0, 0);
  }

#pragma unroll
  for (int mi = 0; mi < 4; mi++) {
#pragma unroll
    for (int ni = 0; ni < 4; ni++) {
      const int col = n0 + wc * 64 + ni * 16 + r16;
      const float bv = bias[col];
      const int rowb = m0 + wr * 64 + mi * 16 + 4 * g;
#pragma unroll
      for (int r = 0; r < 4; r++) {
        const int row = rowb + r;
        const float v = acc[mi][ni][r] + bv;
        if constexpr (EPI == 0) {
          ((float*)out0)[(size_t)row * N + col] = v;
        } else if constexpr (EPI == 1) {
          const int bb = row >> 11, t = row & 2047;
          const int h = col >> 6, d = col & 63;
          ((bf16*)out0)[((size_t)(bb * 16 + h) * 2048 + t) * 64 + d] = (bf16)v;
        } else {
          const int bb = row >> 11, t = row & 2047;
          if (col < 1024) {
            const int h = col >> 6, d = col & 63;
            ((bf16*)out0)[((size_t)(bb * 16 + h) * 2048 + t) * 64 + d] = (bf16)v;
          } else {
            const int c2 = col - 1024;
            const int h = c2 >> 6, d = c2 & 63;
            ((bf16*)out1)[((size_t)(bb * 16 + h) * 2048 + t) * 64 + d] = (bf16)v;
          }
        }
      }
    }
  }
}

// ---------------- causal flash attention ----------------
// Q,K: [bh][t][64] bf16; Vt: [bh][64][s] bf16; Y: [b][t][h*64+d] bf16
__global__ __launch_bounds__(256) void attn_kernel(
    const bf16* __restrict__ Q, const bf16* __restrict__ Kh,
    const bf16* __restrict__ Vt, bf16* __restrict__ Y) {
  __shared__ __align__(16) bf16 Kl[64 * 64];
  __shared__ __align__(16) bf16 Vl[64 * 64];
  __shared__ __align__(16) bf16 Pl[4][16 * 64];

  const int tid = threadIdx.x;
  const int lane = tid & 63;
  const int w = tid >> 6;
  const int g = lane >> 4, r16 = lane & 15;
  const int blk = blockIdx.x;
  const int bh = blk >> 5;
  const int t0 = (blk & 31) * 64;
  const int b = bh >> 4, h = bh & 15;

  bf16x8 qf[2];
  {
    const int trow = t0 + w * 16 + r16;
    const bf16* qp = Q + ((size_t)bh * 2048 + trow) * 64 + g * 8;
    qf[0] = *(const bf16x8*)qp;
    qf[1] = *(const bf16x8*)(qp + 32);
  }

  f32x4 O[4] = {};
  float mrow[4], lsum[4];
#pragma unroll
  for (int r = 0; r < 4; r++) { mrow[r] = -__builtin_inff(); lsum[r] = 0.f; }

  for (int s0 = 0; s0 <= t0; s0 += 64) {
    __syncthreads();
#pragma unroll
    for (int it = 0; it < 2; it++) {
      const int c = tid + it * 256;
      const int rr = c >> 3, ch = c & 7;
      const int sw = ((rr & 7) << 4);
      const bf16x8 kv = *(const bf16x8*)(Kh + ((size_t)bh * 2048 + s0 + rr) * 64 + ch * 8);
      *(bf16x8*)((char*)Kl + rr * 128 + ((ch * 16) ^ sw)) = kv;
      const bf16x8 vv = *(const bf16x8*)(Vt + ((size_t)bh * 64 + rr) * 2048 + s0 + ch * 8);
      *(bf16x8*)((char*)Vl + rr * 128 + ((ch * 16) ^ sw)) = vv;
    }
    __syncthreads();

    f32x4 sacc[4] = {};
#pragma unroll
    for (int sb = 0; sb < 4; sb++) {
      const int srow = sb * 16 + r16;
      const char* kb = (const char*)Kl + srow * 128;
      const int sw = (srow & 7) << 4;
      bf16x8 k0 = *(const bf16x8*)(kb + ((g * 16) ^ sw));
      bf16x8 k1 = *(const bf16x8*)(kb + ((64 + g * 16) ^ sw));
      sacc[sb] = __builtin_amdgcn_mfma_f32_16x16x32_bf16(qf[0], k0, sacc[sb], 0, 0, 0);
      sacc[sb] = __builtin_amdgcn_mfma_f32_16x16x32_bf16(qf[1], k1, sacc[sb], 0, 0, 0);
    }

    float pv[4][4];
    float tmax[4];
#pragma unroll
    for (int r = 0; r < 4; r++) tmax[r] = -__builtin_inff();
    const bool diag = (s0 == t0);
#pragma unroll
    for (int sb = 0; sb < 4; sb++) {
#pragma unroll
      for (int r = 0; r < 4; r++) {
        float v = sacc[sb][r] * 0.125f;
        if (diag) {
          const int s = sb * 16 + r16;
          const int t = w * 16 + 4 * g + r;
          if (s > t) v = -__builtin_inff();
        }
        pv[sb][r] = v;
        tmax[r] = fmaxf(tmax[r], v);
      }
    }
#pragma unroll
    for (int off = 1; off < 16; off <<= 1)
#pragma unroll
      for (int r = 0; r < 4; r++)
        tmax[r] = fmaxf(tmax[r], __shfl_xor(tmax[r], off, 64));

#pragma unroll
    for (int r = 0; r < 4; r++) {
      const float mn = fmaxf(mrow[r], tmax[r]);
      const float sc = __expf(mrow[r] - mn);
      mrow[r] = mn;
      lsum[r] *= sc;
#pragma unroll
      for (int db = 0; db < 4; db++) O[db][r] *= sc;
      float ps = 0.f;
#pragma unroll
      for (int sb = 0; sb < 4; sb++) {
        const float p = __expf(pv[sb][r] - mn);
        pv[sb][r] = p;
        ps += p;
      }
      lsum[r] += ps;
    }

    {
      char* pb = (char*)Pl[w];
#pragma unroll
      for (int sb = 0; sb < 4; sb++)
#pragma unroll
        for (int r = 0; r < 4; r++) {
          const int q = 4 * g + r;
          *(bf16*)(pb + q * 128 + (((sb * 32) + r16 * 2) ^ ((q & 7) << 4))) = (bf16)pv[sb][r];
        }
    }
    __syncthreads();

    {
      const char* pr = (const char*)Pl[w] + r16 * 128;
      const int swq = (r16 & 7) << 4;
      bf16x8 pa0 = *(const bf16x8*)(pr + ((g * 16) ^ swq));
      bf16x8 pa1 = *(const bf16x8*)(pr + ((64 + g * 16) ^ swq));
#pragma unroll
      for (int db = 0; db < 4; db++) {
        const int dr = db * 16 + r16;
        const char* vb = (const char*)Vl + dr * 128;
        const int swd = (dr & 7) << 4;
        bf16x8 v0 = *(const bf16x8*)(vb + ((g * 16) ^ swd));
        bf16x8 v1 = *(const bf16x8*)(vb + ((64 + g * 16) ^ swd));
        O[db] = __builtin_amdgcn_mfma_f32_16x16x32_bf16(pa0, v0, O[db], 0, 0, 0);
        O[db] = __builtin_amdgcn_mfma_f32_16x16x32_bf16(pa1, v1, O[db], 0, 0, 0);
      }
    }
  }

#pragma unroll
  for (int off = 1; off < 16; off <<= 1)
#pragma unroll
    for (int r = 0; r < 4; r++)
      lsum[r] += __shfl_xor(lsum[r], off, 64);

#pragma unroll
  for (int db = 0; db < 4; db++)
#pragma unroll
    for (int r = 0; r < 4; r++) {
      const int t = t0 + w * 16 + 4 * g + r;
      const float v = O[db][r] / lsum[r];
      Y[((size_t)(b * 2048 + t)) * 1024 + h * 64 + db * 16 + r16] = (bf16)v;
    }
}

extern "C" void kernel_launch(void* const* d_in, const int* in_sizes, int n_in,
                              void* d_out, int out_size, void* d_ws, size_t ws_size,
                              hipStream_t stream) {
  (void)in_sizes; (void)n_in; (void)out_size; (void)ws_size;
  const float* x   = (const float*)d_in[0];
  const float* ctx = (const float*)d_in[1];
  const float* Wq  = (const float*)d_in[2];
  const float* bq  = (const float*)d_in[3];
  const float* Wkv = (const float*)d_in[4];
  const float* bkv = (const float*)d_in[5];
  const float* Wp  = (const float*)d_in[6];
  const float* bp  = (const float*)d_in[7];
  float* out = (float*)d_out;

  char* ws = (char*)d_ws;
  const size_t MB = 1024 * 1024;
  bf16* x_bf  = (bf16*)(ws + 0 * MB);
  bf16* c_bf  = (bf16*)(ws + 8 * MB);
  bf16* Wq_t  = (bf16*)(ws + 16 * MB);
  bf16* Wkv_t = (bf16*)(ws + 18 * MB);
  bf16* Wp_t  = (bf16*)(ws + 22 * MB);
  bf16* Qh    = (bf16*)(ws + 24 * MB);
  bf16* Kh    = (bf16*)(ws + 32 * MB);
  bf16* Vh    = (bf16*)(ws + 40 * MB);
  bf16* Vt    = (bf16*)(ws + 48 * MB);
  bf16* y_bf  = (bf16*)(ws + 56 * MB);

  const int n = 2 * 2048 * 1024;
  cast_bf16_kernel<<<(n / 4 + 255) / 256, 256, 0, stream>>>(x, x_bf, n / 4);
  cast_bf16_kernel<<<(n / 4 + 255) / 256, 256, 0, stream>>>(ctx, c_bf, n / 4);
  transpose_cast_w<<<dim3(32, 32), dim3(32, 8), 0, stream>>>(Wq, Wq_t, 1024, 1024);
  transpose_cast_w<<<dim3(64, 32), dim3(32, 8), 0, stream>>>(Wkv, Wkv_t, 1024, 2048);
  transpose_cast_w<<<dim3(32, 32), dim3(32, 8), 0, stream>>>(Wp, Wp_t, 1024, 1024);
  gemm_bf16_kernel<1><<<dim3(8, 32), 256, 0, stream>>>(x_bf, Wq_t, bq, Qh, nullptr, 4096, 1024, 1024);
  gemm_bf16_kernel<2><<<dim3(16, 32), 256, 0, stream>>>(c_bf, Wkv_t, bkv, Kh, Vh, 4096, 2048, 1024);
  vtrans_kernel<<<dim3(64, 2, 32), dim3(32, 8), 0, stream>>>(Vh, Vt);
  attn_kernel<<<1024, 256, 0, stream>>>(Qh, Kh, Vt, y_bf);
  gemm_bf16_kernel<0><<<dim3(8, 32), 256, 0, stream>>>(y_bf, Wp_t, bp, out, nullptr, 4096, 1024, 1024);
}

// Round 2
// 163.504 us; speedup vs baseline: 1.2307x; 1.2307x over previous
//
#include <hip/hip_runtime.h>
#include <hip/hip_bf16.h>

typedef __bf16 bf16;
typedef __bf16 bf16x8 __attribute__((ext_vector_type(8)));
typedef __bf16 bf16x4 __attribute__((ext_vector_type(4)));
typedef float f32x4 __attribute__((ext_vector_type(4)));
typedef float f32x16 __attribute__((ext_vector_type(16)));

#define GLOAD_LDS16(g, l) \
  __builtin_amdgcn_global_load_lds((const __attribute__((address_space(1))) void*)(g), \
                                   (__attribute__((address_space(3))) void*)(l), 16, 0, 0)

static __device__ __forceinline__ unsigned cvtpk_bf16(float lo, float hi) {
  unsigned r;
  asm("v_cvt_pk_bf16_f32 %0, %1, %2" : "=v"(r) : "v"(lo), "v"(hi));
  return r;
}
static __device__ __forceinline__ void pl32swap(unsigned& a, unsigned& b) {
  asm volatile("v_permlane32_swap_b32 %0, %1" : "+v"(a), "+v"(b));
}

// ---------------- cast f32 -> bf16 (vectorized) ----------------
__global__ void cast_bf16_kernel(const float* __restrict__ in, bf16* __restrict__ out, int n4) {
  int i = blockIdx.x * blockDim.x + threadIdx.x;
  if (i >= n4) return;
  float4 v = ((const float4*)in)[i];
  bf16x4 o;
  o.x = (bf16)v.x; o.y = (bf16)v.y; o.z = (bf16)v.z; o.w = (bf16)v.w;
  ((bf16x4*)out)[i] = o;
}

// ---------------- transpose + cast weights: W[K][N] f32 -> Wt[N][K] bf16 ----------------
__global__ void transpose_cast_w(const float* __restrict__ W, bf16* __restrict__ Wt, int K, int N) {
  __shared__ float tile[32][33];
  const int n0 = blockIdx.x * 32, k0 = blockIdx.y * 32;
  const int tx = threadIdx.x, ty = threadIdx.y;
#pragma unroll
  for (int i = 0; i < 32; i += 8)
    tile[ty + i][tx] = W[(size_t)(k0 + ty + i) * N + n0 + tx];
  __syncthreads();
#pragma unroll
  for (int i = 0; i < 32; i += 8)
    Wt[(size_t)(n0 + ty + i) * K + k0 + tx] = (bf16)tile[tx][ty + i];
}

// ---------------- V transpose: V[bh][s][d] -> Vt[bh][d][s] (bf16) ----------------
__global__ void vtrans_kernel(const bf16* __restrict__ V, bf16* __restrict__ Vt) {
  __shared__ bf16 tile[32][34];
  const int bh = blockIdx.z;
  const int s0 = blockIdx.x * 32, d0 = blockIdx.y * 32;
  const int tx = threadIdx.x, ty = threadIdx.y;
#pragma unroll
  for (int i = 0; i < 32; i += 8)
    tile[ty + i][tx] = V[((size_t)bh * 2048 + s0 + ty + i) * 64 + d0 + tx];
  __syncthreads();
#pragma unroll
  for (int i = 0; i < 32; i += 8)
    Vt[((size_t)bh * 64 + d0 + ty + i) * 2048 + s0 + tx] = tile[tx][ty + i];
}

// ---------------- GEMM: C[M][N] = A[M][K] * Bt[N][K]^T + bias ----------------
// EPI 0: fp32 out, natural layout. EPI 1: bf16 out in [bh][t][d] (Q, pre-scaled by 0.125).
// EPI 2: split KV -> K,V [bh][s][d].
template <int EPI>
__global__ __launch_bounds__(256) void gemm_bf16_kernel(
    const bf16* __restrict__ A, const bf16* __restrict__ Bt,
    const float* __restrict__ bias,
    void* __restrict__ out0, void* __restrict__ out1,
    int M, int N, int K) {
  __shared__ __align__(16) bf16 As[128 * 32];
  __shared__ __align__(16) bf16 Bs[128 * 32];

  const int tid = threadIdx.x;
  const int lane = tid & 63;
  const int w = tid >> 6;
  const int wr = w >> 1, wc = w & 1;
  const int g = lane >> 4, r16 = lane & 15;
  const int m0 = blockIdx.y * 128, n0 = blockIdx.x * 128;

  const int c0 = tid, c1 = tid + 256;
  const bf16* Ag0 = A + (size_t)(m0 + (c0 >> 2)) * K + (c0 & 3) * 8;
  const bf16* Ag1 = A + (size_t)(m0 + (c1 >> 2)) * K + (c1 & 3) * 8;
  const bf16* Bg0 = Bt + (size_t)(n0 + (c0 >> 2)) * K + (c0 & 3) * 8;
  const bf16* Bg1 = Bt + (size_t)(n0 + (c1 >> 2)) * K + (c1 & 3) * 8;
  bf16* As0 = As + w * 512;
  bf16* As1 = As + 2048 + w * 512;
  bf16* Bs0 = Bs + w * 512;
  bf16* Bs1 = Bs + 2048 + w * 512;

  f32x4 acc[4][4] = {};

  for (int k0 = 0; k0 < K; k0 += 32) {
    __syncthreads();
    GLOAD_LDS16(Ag0 + k0, As0);
    GLOAD_LDS16(Ag1 + k0, As1);
    GLOAD_LDS16(Bg0 + k0, Bs0);
    GLOAD_LDS16(Bg1 + k0, Bs1);
    __syncthreads();
    bf16x8 af[4], bfr[4];
#pragma unroll
    for (int i = 0; i < 4; i++)
      af[i] = *(const bf16x8*)(As + (wr * 64 + i * 16 + r16) * 32 + g * 8);
#pragma unroll
    for (int i = 0; i < 4; i++)
      bfr[i] = *(const bf16x8*)(Bs + (wc * 64 + i * 16 + r16) * 32 + g * 8);
#pragma unroll
    for (int mi = 0; mi < 4; mi++)
#pragma unroll
      for (int ni = 0; ni < 4; ni++)
        acc[mi][ni] = __builtin_amdgcn_mfma_f32_16x16x32_bf16(af[mi], bfr[ni], acc[mi][ni], 0, 0, 0);
  }

#pragma unroll
  for (int mi = 0; mi < 4; mi++) {
#pragma unroll
    for (int ni = 0; ni < 4; ni++) {
      const int col = n0 + wc * 64 + ni * 16 + r16;
      const float bv = bias[col];
      const int rowb = m0 + wr * 64 + mi * 16 + 4 * g;
#pragma unroll
      for (int r = 0; r < 4; r++) {
        const int row = rowb + r;
        const float v = acc[mi][ni][r] + bv;
        if constexpr (EPI == 0) {
          ((float*)out0)[(size_t)row * N + col] = v;
        } else if constexpr (EPI == 1) {
          const int bb = row >> 11, t = row & 2047;
          const int h = col >> 6, d = col & 63;
          // pre-scale Q by 1/sqrt(D) = 0.125 (exact in bf16: exponent shift)
          ((bf16*)out0)[((size_t)(bb * 16 + h) * 2048 + t) * 64 + d] = (bf16)(v * 0.125f);
        } else {
          const int bb = row >> 11, t = row & 2047;
          if (col < 1024) {
            const int h = col >> 6, d = col & 63;
            ((bf16*)out0)[((size_t)(bb * 16 + h) * 2048 + t) * 64 + d] = (bf16)v;
          } else {
            const int c2 = col - 1024;
            const int h = c2 >> 6, d = c2 & 63;
            ((bf16*)out1)[((size_t)(bb * 16 + h) * 2048 + t) * 64 + d] = (bf16)v;
          }
        }
      }
    }
  }
}

// ---------------- causal flash attention, 4 warps x 32 q-rows, 32x32x16 MFMA ----------------
// Q (pre-scaled): [bh][t][64] bf16; K: [bh][s][64] bf16; Vt: [bh][64][s] bf16
// Y: [b][t][h*64+d] bf16
// Swapped QK^T (mfma(K,Q)) -> lane holds P row for q=lane&31; in-register softmax;
// P->bf16 via cvt_pk + permlane32_swap; defer-max (THR=8); 2-phase LDS double buffer.
__global__ __launch_bounds__(256) void attn_kernel(
    const bf16* __restrict__ Q, const bf16* __restrict__ Kh,
    const bf16* __restrict__ Vt, bf16* __restrict__ Y) {
  __shared__ __align__(16) bf16 Kls[2][4096];
  __shared__ __align__(16) bf16 Vls[2][4096];

  const int tid = threadIdx.x;
  const int lane = tid & 63;
  const int w = tid >> 6;           // warp 0..3
  const int l31 = lane & 31;
  const int g = lane >> 5;          // 0/1
  const int blk = blockIdx.x;
  const int c = 15 - (blk >> 5);    // q-chunk 0..15, longest-first dispatch
  const int bh = blk & 31;
  const int b = bh >> 4, h = bh & 15;
  const int qb = c * 128;
  const int wq = qb + w * 32;       // warp's first q row
  const int nt = 2 * c + 2;         // KV tiles of 64

  // Q fragments (B-operand): lane holds Q[wq + l31][cc*16 + g*8 + j]
  bf16x8 qf[4];
  {
    const bf16* qp = Q + ((size_t)bh * 2048 + wq + l31) * 64 + g * 8;
#pragma unroll
    for (int cc = 0; cc < 4; ++cc) qf[cc] = *(const bf16x8*)(qp + cc * 16);
  }

  f32x16 O0 = {}, O1 = {};
  float m = -3.0e38f, l = 0.f;

  auto stage = [&](int bi, int s0) {
#pragma unroll
    for (int it = 0; it < 2; ++it) {
      const int sg = w * 64 + lane + it * 256;    // 16B-slot index 0..511
      const int s = sg >> 3, j = sg & 7;
      const int js = (j ^ (s & 7)) * 8;           // pre-swizzled global source (rule #21)
      GLOAD_LDS16(Kh + ((size_t)bh * 2048 + s0 + s) * 64 + js, &Kls[bi][sg * 8]);
      GLOAD_LDS16(Vt + ((size_t)bh * 64 + s) * 2048 + s0 + js, &Vls[bi][sg * 8]);
    }
  };

  stage(0, 0);
  __syncthreads();

  int buf = 0;
  for (int t = 0; t < nt; ++t) {
    const int s0 = t * 64;
    if (t + 1 < nt) stage(buf ^ 1, s0 + 64);   // prefetch next tile (other buffer)

    if (s0 < wq + 32) {                        // else: fully masked tile for this warp
      const bf16* Kb = Kls[buf];
      const bf16* Vb = Vls[buf];

      // ---- QK^T swapped: S^T[s][q], q = lane&31, s = (r&3)+8*(r>>2)+4g (+32 for SB)
      f32x16 SA = {}, SB = {};
#pragma unroll
      for (int cc = 0; cc < 4; ++cc) {
        const int sl = ((cc * 2 + g) ^ (l31 & 7)) * 8;
        bf16x8 kf0 = *(const bf16x8*)(Kb + l31 * 64 + sl);
        SA = __builtin_amdgcn_mfma_f32_32x32x16_bf16(kf0, qf[cc], SA, 0, 0, 0);
        bf16x8 kf1 = *(const bf16x8*)(Kb + (32 + l31) * 64 + sl);
        SB = __builtin_amdgcn_mfma_f32_32x32x16_bf16(kf1, qf[cc], SB, 0, 0, 0);
      }

      const int qg = wq + l31;  // this lane's q row (softmax state index)
      if (s0 + 63 > wq) {       // diagonal overlap: apply causal mask
#pragma unroll
        for (int r = 0; r < 16; ++r) {
          const int sl = (r & 3) + 8 * (r >> 2) + 4 * g;
          SA[r] = (s0 + sl <= qg) ? SA[r] : -3.0e38f;
          SB[r] = (s0 + 32 + sl <= qg) ? SB[r] : -3.0e38f;
        }
      }

      // ---- row max: in-lane over 32 + one cross-half swap
      float pmax = -3.0e38f;
#pragma unroll
      for (int r = 0; r < 16; ++r) pmax = fmaxf(pmax, fmaxf(SA[r], SB[r]));
      pmax = fmaxf(pmax, __shfl_xor(pmax, 32, 64));

      // ---- defer-max (T13, THR=8): rescale O only when max grew too much
      if (!__all(pmax <= m + 8.f)) {
        const float mn = fmaxf(m, pmax);
        const float f = __expf(m - mn);
        m = mn;
        l *= f;
#pragma unroll
        for (int r = 0; r < 16; ++r) {
          const int qr = (r & 3) + 8 * (r >> 2) + (g << 2);  // O-reg r's q row
          const float fr = __shfl(f, qr, 64);
          O0[r] *= fr;
          O1[r] *= fr;
        }
      }

      // ---- P = exp(S - m), accumulate l
      float ps = 0.f;
#pragma unroll
      for (int r = 0; r < 16; ++r) { SA[r] = __expf(SA[r] - m); ps += SA[r]; }
#pragma unroll
      for (int r = 0; r < 16; ++r) { SB[r] = __expf(SB[r] - m); ps += SB[r]; }
      l += ps;

      // ---- P -> bf16 A-fragments via cvt_pk + permlane32_swap (T12)
      union PW { unsigned u[4]; bf16x8 v; };
      PW pa0, pa1, pa2, pa3;
      {
        unsigned A0 = cvtpk_bf16(SA[0], SA[1]), B0 = cvtpk_bf16(SA[2], SA[3]);
        unsigned C0 = cvtpk_bf16(SA[4], SA[5]), D0 = cvtpk_bf16(SA[6], SA[7]);
        pl32swap(A0, C0); pl32swap(B0, D0);
        pa0.u[0] = A0; pa0.u[1] = B0; pa0.u[2] = C0; pa0.u[3] = D0;

        unsigned A1 = cvtpk_bf16(SA[8], SA[9]), B1 = cvtpk_bf16(SA[10], SA[11]);
        unsigned C1 = cvtpk_bf16(SA[12], SA[13]), D1 = cvtpk_bf16(SA[14], SA[15]);
        pl32swap(A1, C1); pl32swap(B1, D1);
        pa1.u[0] = A1; pa1.u[1] = B1; pa1.u[2] = C1; pa1.u[3] = D1;

        unsigned A2 = cvtpk_bf16(SB[0], SB[1]), B2 = cvtpk_bf16(SB[2], SB[3]);
        unsigned C2 = cvtpk_bf16(SB[4], SB[5]), D2 = cvtpk_bf16(SB[6], SB[7]);
        pl32swap(A2, C2); pl32swap(B2, D2);
        pa2.u[0] = A2; pa2.u[1] = B2; pa2.u[2] = C2; pa2.u[3] = D2;

        unsigned A3 = cvtpk_bf16(SB[8], SB[9]), B3 = cvtpk_bf16(SB[10], SB[11]);
        unsigned C3 = cvtpk_bf16(SB[12], SB[13]), D3 = cvtpk_bf16(SB[14], SB[15]);
        pl32swap(A3, C3); pl32swap(B3, D3);
        pa3.u[0] = A3; pa3.u[1] = B3; pa3.u[2] = C3; pa3.u[3] = D3;
      }

      // ---- PV: O[q][d] += P[q][s] V[s][d]; B-frag = Vt rows from LDS
#pragma unroll
      for (int cc = 0; cc < 4; ++cc) {
        const bf16x8 pav = (cc == 0) ? pa0.v : (cc == 1) ? pa1.v : (cc == 2) ? pa2.v : pa3.v;
        {
          const int sl = ((cc * 2 + g) ^ (l31 & 7)) * 8;
          bf16x8 vf0 = *(const bf16x8*)(Vb + l31 * 64 + sl);
          O0 = __builtin_amdgcn_mfma_f32_32x32x16_bf16(pav, vf0, O0, 0, 0, 0);
          bf16x8 vf1 = *(const bf16x8*)(Vb + (32 + l31) * 64 + sl);
          O1 = __builtin_amdgcn_mfma_f32_32x32x16_bf16(pav, vf1, O1, 0, 0, 0);
        }
      }
    }

    __syncthreads();   // staged tile complete (vmcnt+lgkm drained by syncthreads)
    buf ^= 1;
  }

  // ---- epilogue: combine lane halves of l, normalize, store
  l += __shfl_xor(l, 32, 64);
#pragma unroll
  for (int r = 0; r < 16; ++r) {
    const int qr = (r & 3) + 8 * (r >> 2) + (g << 2);
    const float lr = __shfl(l, qr, 64);
    const float inv = 1.f / lr;
    const int tq = wq + qr;
    bf16* yp = Y + ((size_t)(b * 2048 + tq)) * 1024 + h * 64 + l31;
    yp[0]  = (bf16)(O0[r] * inv);
    yp[32] = (bf16)(O1[r] * inv);
  }
}

extern "C" void kernel_launch(void* const* d_in, const int* in_sizes, int n_in,
                              void* d_out, int out_size, void* d_ws, size_t ws_size,
                              hipStream_t stream) {
  (void)in_sizes; (void)n_in; (void)out_size; (void)ws_size;
  const float* x   = (const float*)d_in[0];
  const float* ctx = (const float*)d_in[1];
  const float* Wq  = (const float*)d_in[2];
  const float* bq  = (const float*)d_in[3];
  const float* Wkv = (const float*)d_in[4];
  const float* bkv = (const float*)d_in[5];
  const float* Wp  = (const float*)d_in[6];
  const float* bp  = (const float*)d_in[7];
  float* out = (float*)d_out;

  char* ws = (char*)d_ws;
  const size_t MB = 1024 * 1024;
  bf16* x_bf  = (bf16*)(ws + 0 * MB);
  bf16* c_bf  = (bf16*)(ws + 8 * MB);
  bf16* Wq_t  = (bf16*)(ws + 16 * MB);
  bf16* Wkv_t = (bf16*)(ws + 18 * MB);
  bf16* Wp_t  = (bf16*)(ws + 22 * MB);
  bf16* Qh    = (bf16*)(ws + 24 * MB);
  bf16* Kh    = (bf16*)(ws + 32 * MB);
  bf16* Vh    = (bf16*)(ws + 40 * MB);
  bf16* Vt    = (bf16*)(ws + 48 * MB);
  bf16* y_bf  = (bf16*)(ws + 56 * MB);

  const int n = 2 * 2048 * 1024;
  cast_bf16_kernel<<<(n / 4 + 255) / 256, 256, 0, stream>>>(x, x_bf, n / 4);
  cast_bf16_kernel<<<(n / 4 + 255) / 256, 256, 0, stream>>>(ctx, c_bf, n / 4);
  transpose_cast_w<<<dim3(32, 32), dim3(32, 8), 0, stream>>>(Wq, Wq_t, 1024, 1024);
  transpose_cast_w<<<dim3(64, 32), dim3(32, 8), 0, stream>>>(Wkv, Wkv_t, 1024, 2048);
  transpose_cast_w<<<dim3(32, 32), dim3(32, 8), 0, stream>>>(Wp, Wp_t, 1024, 1024);
  gemm_bf16_kernel<1><<<dim3(8, 32), 256, 0, stream>>>(x_bf, Wq_t, bq, Qh, nullptr, 4096, 1024, 1024);
  gemm_bf16_kernel<2><<<dim3(16, 32), 256, 0, stream>>>(c_bf, Wkv_t, bkv, Kh, Vh, 4096, 2048, 1024);
  vtrans_kernel<<<dim3(64, 2, 32), dim3(32, 8), 0, stream>>>(Vh, Vt);
  attn_kernel<<<512, 256, 0, stream>>>(Qh, Kh, Vt, y_bf);
  gemm_bf16_kernel<0><<<dim3(8, 32), 256, 0, stream>>>(y_bf, Wp_t, bp, out, nullptr, 4096, 1024, 1024);
}